// Round 1
// baseline (155.348 us; speedup 1.0000x reference)
//
#include <hip/hip_runtime.h>

#define B_    32
#define N_    10000
#define G_    256
#define HID_  256
#define Z_    256
#define EPS_  1e-5f
#define CH_   128
#define NCH_  ((N_ + CH_ - 1) / CH_)   // 79

// ---------------------------------------------------------------------------
// Tiled transpose: src is R x C row-major -> dst is C x R row-major.
// ---------------------------------------------------------------------------
__global__ __launch_bounds__(256) void transpose_k(const float* __restrict__ src,
                                                   float* __restrict__ dst,
                                                   int R, int C) {
    __shared__ float tile[32][33];   // +1 pad: no bank conflicts
    int c0 = blockIdx.x * 32, r0 = blockIdx.y * 32;
    int tx = threadIdx.x, ty = threadIdx.y;   // block (32, 8)
#pragma unroll
    for (int j = 0; j < 4; ++j) {
        int r = r0 + ty + j * 8, c = c0 + tx;
        if (r < R && c < C) tile[ty + j * 8][tx] = src[(size_t)r * C + c];
    }
    __syncthreads();
#pragma unroll
    for (int j = 0; j < 4; ++j) {
        int c = c0 + ty + j * 8, r = r0 + tx;
        if (r < R && c < C) dst[(size_t)c * R + r] = tile[tx][ty + j * 8];
    }
}

// ---------------------------------------------------------------------------
// Per-group compaction of the binary mask into index lists (order-free).
// ---------------------------------------------------------------------------
__global__ __launch_bounds__(256) void compact_k(const float* __restrict__ mask,
                                                 int* __restrict__ cnt,
                                                 unsigned short* __restrict__ idx) {
    int g = blockIdx.x;
    __shared__ int c;
    if (threadIdx.x == 0) c = 0;
    __syncthreads();
    for (int n = threadIdx.x; n < N_; n += 256) {
        if (mask[(size_t)g * N_ + n] != 0.0f) {
            int p = atomicAdd(&c, 1);
            idx[(size_t)g * N_ + p] = (unsigned short)n;
        }
    }
    __syncthreads();
    if (threadIdx.x == 0) cnt[g] = c;
}

// ---------------------------------------------------------------------------
// h[b,g,c] = b1[c]   (bias pre-init; spacc atomically accumulates on top)
// ---------------------------------------------------------------------------
__global__ __launch_bounds__(256) void inith_k(float* __restrict__ h,
                                               const float* __restrict__ b1) {
    int i = blockIdx.x * 256 + threadIdx.x;
    if (i < B_ * G_ * HID_) h[i] = b1[i & (HID_ - 1)];
}

// ---------------------------------------------------------------------------
// Sparse accumulate: h[b,g,t] += sum_{n in idx[g, k0..k1)} x[b,n] * W1[t,n]
// One block per (chunk, group); thread t owns HID column t, 32 b-accumulators.
// ---------------------------------------------------------------------------
__global__ __launch_bounds__(256) void spacc_k(const float* __restrict__ w1t,
                                               const float* __restrict__ xt,
                                               const int* __restrict__ cnt,
                                               const unsigned short* __restrict__ idx,
                                               float* __restrict__ h) {
    int g = blockIdx.y;
    int count = cnt[g];
    int k0 = blockIdx.x * CH_;
    if (k0 >= count) return;
    int k1 = min(count, k0 + CH_);
    int t = threadIdx.x;

    float acc[B_];
#pragma unroll
    for (int b = 0; b < B_; ++b) acc[b] = 0.f;

    for (int k = k0; k < k1; ++k) {
        int n = idx[(size_t)g * N_ + k];            // uniform per block
        float w = w1t[(size_t)n * HID_ + t];        // coalesced 1KB / block
        const float4* xr = reinterpret_cast<const float4*>(xt + (size_t)n * B_);
#pragma unroll
        for (int q = 0; q < B_ / 4; ++q) {
            float4 xv = xr[q];                       // broadcast loads
            acc[4 * q + 0] += xv.x * w;
            acc[4 * q + 1] += xv.y * w;
            acc[4 * q + 2] += xv.z * w;
            acc[4 * q + 3] += xv.w * w;
        }
    }
#pragma unroll
    for (int b = 0; b < B_; ++b)
        atomicAdd(&h[((size_t)b * G_ + g) * HID_ + t], acc[b]);
}

// ---------------------------------------------------------------------------
// BatchNorm (per-g stats over (B, 256)) + ReLU, in place. Block per g.
// ---------------------------------------------------------------------------
__global__ __launch_bounds__(256) void bnrelu_k(float* __restrict__ buf,
                                                const float* __restrict__ gamma,
                                                const float* __restrict__ beta) {
    int g = blockIdx.x, t = threadIdx.x;
    float v[B_];
    float s = 0.f, ss = 0.f;
#pragma unroll
    for (int b = 0; b < B_; ++b) {
        float xv = buf[((size_t)b * G_ + g) * HID_ + t];
        v[b] = xv;
        s += xv;
        ss += xv * xv;
    }
#pragma unroll
    for (int o = 32; o > 0; o >>= 1) {
        s  += __shfl_down(s, o);
        ss += __shfl_down(ss, o);
    }
    __shared__ float rs[4], rss[4];
    int wave = t >> 6, lane = t & 63;
    if (lane == 0) { rs[wave] = s; rss[wave] = ss; }
    __syncthreads();
    float S  = rs[0] + rs[1] + rs[2] + rs[3];
    float SS = rss[0] + rss[1] + rss[2] + rss[3];
    const float inv = 1.0f / (float)(B_ * HID_);
    float mean = S * inv;
    float var  = SS * inv - mean * mean;       // biased, matches jnp.var
    float sc = gamma[g] * rsqrtf(var + EPS_);
    float sh = beta[g] - mean * sc;
#pragma unroll
    for (int b = 0; b < B_; ++b) {
        float y = v[b] * sc + sh;
        buf[((size_t)b * G_ + g) * HID_ + t] = fmaxf(y, 0.f);
    }
}

// ---------------------------------------------------------------------------
// z[row, t] = b2[t] + sum_c h[row, c] * W2[t, c]   (row = b*G+g), 8 rows/block
// ---------------------------------------------------------------------------
#define ROWS_ 8
__global__ __launch_bounds__(256) void gemm2_k(const float* __restrict__ h,
                                               const float* __restrict__ w2t,
                                               const float* __restrict__ b2,
                                               float* __restrict__ z) {
    int row0 = blockIdx.x * ROWS_, t = threadIdx.x;
    __shared__ float lh[ROWS_][HID_];
#pragma unroll
    for (int r = 0; r < ROWS_; ++r) lh[r][t] = h[((size_t)row0 + r) * HID_ + t];
    __syncthreads();
    float bb = b2[t];
    float acc[ROWS_];
#pragma unroll
    for (int r = 0; r < ROWS_; ++r) acc[r] = bb;
    for (int c = 0; c < HID_; ++c) {
        float w = w2t[(size_t)c * Z_ + t];           // coalesced, reused x8
#pragma unroll
        for (int r = 0; r < ROWS_; ++r) acc[r] += lh[r][c] * w;  // LDS broadcast
    }
#pragma unroll
    for (int r = 0; r < ROWS_; ++r)
        z[((size_t)row0 + r) * Z_ + t] = acc[r];
}

// ---------------------------------------------------------------------------
extern "C" void kernel_launch(void* const* d_in, const int* in_sizes, int n_in,
                              void* d_out, int out_size, void* d_ws, size_t ws_size,
                              hipStream_t stream) {
    const float* x    = (const float*)d_in[0];
    const float* mask = (const float*)d_in[1];
    const float* W1   = (const float*)d_in[2];
    const float* b1   = (const float*)d_in[3];
    const float* g1   = (const float*)d_in[4];
    const float* be1  = (const float*)d_in[5];
    const float* W2   = (const float*)d_in[6];
    const float* b2   = (const float*)d_in[7];
    const float* g2   = (const float*)d_in[8];
    const float* be2  = (const float*)d_in[9];
    float* out = (float*)d_out;

    char* ws = (char*)d_ws;
    size_t off = 0;
    auto take = [&](size_t bytes) {
        char* p = ws + off;
        off = (off + bytes + 255) & ~(size_t)255;
        return p;
    };
    float* w1t          = (float*)take((size_t)N_ * HID_ * 4);   // (N, HID)
    float* xt           = (float*)take((size_t)N_ * B_ * 4);     // (N, B)
    float* w2t          = (float*)take((size_t)HID_ * Z_ * 4);   // (HID, Z)
    float* h            = (float*)take((size_t)B_ * G_ * HID_ * 4);
    int* cnt            = (int*)take((size_t)G_ * 4);
    unsigned short* idx = (unsigned short*)take((size_t)G_ * N_ * 2);

    dim3 tb(32, 8);
    // W1 (HID x N) -> w1t (N x HID)
    transpose_k<<<dim3((N_ + 31) / 32, (HID_ + 31) / 32), tb, 0, stream>>>(W1, w1t, HID_, N_);
    // x (B x N) -> xt (N x B)
    transpose_k<<<dim3((N_ + 31) / 32, (B_ + 31) / 32), tb, 0, stream>>>(x, xt, B_, N_);
    // W2 (Z x HID) -> w2t (HID x Z)
    transpose_k<<<dim3((HID_ + 31) / 32, (Z_ + 31) / 32), tb, 0, stream>>>(W2, w2t, Z_, HID_);

    compact_k<<<G_, 256, 0, stream>>>(mask, cnt, idx);
    inith_k<<<(B_ * G_ * HID_ + 255) / 256, 256, 0, stream>>>(h, b1);
    spacc_k<<<dim3(NCH_, G_), 256, 0, stream>>>(w1t, xt, cnt, idx, h);
    bnrelu_k<<<G_, 256, 0, stream>>>(h, g1, be1);
    gemm2_k<<<(B_ * G_) / ROWS_, 256, 0, stream>>>(h, w2t, b2, out);
    bnrelu_k<<<G_, 256, 0, stream>>>(out, g2, be2);
}

// Round 2
// 148.908 us; speedup vs baseline: 1.0432x; 1.0432x over previous
//
#include <hip/hip_runtime.h>

#define B_    32
#define N_    10000
#define G_    256
#define HID_  256
#define Z_    256
#define EPS_  1e-5f
#define CH_   128

// prep_k grid segmentation
#define TB_W1  2504            // 313 col-tiles x 8 row-tiles (W1: 256 x 10000)
#define TB_X   313             // x: 32 x 10000
#define TB_W2  64              // W2: 256 x 256
#define NB_H   2048            // h init: 512K float4 / 256
#define NB_CMP 256             // mask compaction, one block per g
#define PREP_GRID (TB_W1 + TB_X + TB_W2 + NB_H + NB_CMP)   // 5185

// ---------------------------------------------------------------------------
// Fused prep: W1/x/W2 transposes + h=b1 broadcast init + mask compaction
// (also builds the spacc worklist).
// ---------------------------------------------------------------------------
__device__ inline void transpose_tile(const float* __restrict__ src,
                                      float* __restrict__ dst,
                                      int R, int C, int bx, int by, int t,
                                      float (*tile)[33]) {
    int tx = t & 31, ty = t >> 5;      // 32 x 8
    int c0 = bx * 32, r0 = by * 32;
#pragma unroll
    for (int j = 0; j < 4; ++j) {
        int r = r0 + ty + j * 8, c = c0 + tx;
        if (r < R && c < C) tile[ty + j * 8][tx] = src[(size_t)r * C + c];
    }
    __syncthreads();
#pragma unroll
    for (int j = 0; j < 4; ++j) {
        int c = c0 + ty + j * 8, r = r0 + tx;
        if (r < R && c < C) dst[(size_t)c * R + r] = tile[tx][ty + j * 8];
    }
}

__global__ __launch_bounds__(256) void prep_k(const float* __restrict__ W1,
                                              const float* __restrict__ x,
                                              const float* __restrict__ W2,
                                              const float* __restrict__ mask,
                                              const float* __restrict__ b1,
                                              float* __restrict__ w1t,
                                              float* __restrict__ xt,
                                              float* __restrict__ w2t,
                                              float4* __restrict__ h4,
                                              int* __restrict__ cnt,
                                              unsigned short* __restrict__ idx,
                                              int* __restrict__ work,
                                              int* __restrict__ nwork) {
    __shared__ float tile[32][33];
    __shared__ int c;
    int bid = blockIdx.x, t = threadIdx.x;

    if (bid < TB_W1) {
        transpose_tile(W1, w1t, HID_, N_, bid % 313, bid / 313, t, tile);
    } else if (bid < TB_W1 + TB_X) {
        transpose_tile(x, xt, B_, N_, bid - TB_W1, 0, t, tile);
    } else if (bid < TB_W1 + TB_X + TB_W2) {
        int b = bid - (TB_W1 + TB_X);
        transpose_tile(W2, w2t, Z_, HID_, b % 8, b / 8, t, tile);
    } else if (bid < TB_W1 + TB_X + TB_W2 + NB_H) {
        int i = (bid - (TB_W1 + TB_X + TB_W2)) * 256 + t;   // < 524288
        const float4* b1_4 = (const float4*)b1;
        h4[i] = b1_4[i & 63];
    } else {
        int g = bid - (TB_W1 + TB_X + TB_W2 + NB_H);
        if (t == 0) c = 0;
        __syncthreads();
        for (int n = t; n < N_; n += 256) {
            if (mask[(size_t)g * N_ + n] != 0.0f) {
                int p = atomicAdd(&c, 1);
                idx[(size_t)g * N_ + p] = (unsigned short)n;
            }
        }
        __syncthreads();
        if (t == 0) {
            cnt[g] = c;
            int nch = (c + CH_ - 1) / CH_;
            int base = atomicAdd(nwork, nch);
            for (int j = 0; j < nch; ++j) work[base + j] = (g << 16) | j;
        }
    }
}

// ---------------------------------------------------------------------------
// Sparse accumulate over worklist. Thread = (4 HID cols) x (8 batches).
// x rows staged coalesced in LDS; inner loop: 1 coalesced float4 w-load +
// 2 LDS broadcast reads + 32 FMAs per gene.
// ---------------------------------------------------------------------------
__global__ __launch_bounds__(256) void spacc_k(const float4* __restrict__ w1t4,
                                               const float4* __restrict__ xt4,
                                               const int* __restrict__ cnt,
                                               const unsigned short* __restrict__ idx,
                                               const int* __restrict__ work,
                                               const int* __restrict__ nwork,
                                               float* __restrict__ h) {
    __shared__ float4 xs[CH_][9];      // [gene][b/4], padded row to break bank aliasing
    __shared__ int ns[CH_];
    const int t  = threadIdx.x;
    const int tc = t & 63;             // owns cols 4*tc .. 4*tc+3
    const int tb = t >> 6;             // owns batches 8*tb .. 8*tb+7 (wave-uniform)
    const int NW = *nwork;

    for (int item = blockIdx.x; item < NW; item += gridDim.x) {
        __syncthreads();               // protect LDS reuse across items
        int wk = work[item];
        int g  = wk >> 16;
        int k0 = (wk & 0xffff) * CH_;
        int kn = min(cnt[g] - k0, CH_);

        if (t < kn) ns[t] = idx[(size_t)g * N_ + k0 + t];
        __syncthreads();
        for (int base = 0; base < kn; base += 32) {
            int k = base + (t >> 3);
            if (k < kn) xs[k][t & 7] = xt4[(size_t)ns[k] * 8 + (t & 7)];
        }
        __syncthreads();

        float4 acc[8];
#pragma unroll
        for (int j = 0; j < 8; ++j) acc[j] = make_float4(0.f, 0.f, 0.f, 0.f);

#pragma unroll 2
        for (int k = 0; k < kn; ++k) {
            float4 wv = w1t4[(size_t)ns[k] * 64 + tc];   // coalesced 1KB/wave
            float4 xa = xs[k][2 * tb];                    // LDS broadcast
            float4 xb = xs[k][2 * tb + 1];
            float xv[8] = {xa.x, xa.y, xa.z, xa.w, xb.x, xb.y, xb.z, xb.w};
#pragma unroll
            for (int j = 0; j < 8; ++j) {
                acc[j].x += xv[j] * wv.x;
                acc[j].y += xv[j] * wv.y;
                acc[j].z += xv[j] * wv.z;
                acc[j].w += xv[j] * wv.w;
            }
        }

#pragma unroll
        for (int j = 0; j < 8; ++j) {
            int b = tb * 8 + j;
            float* hp = h + ((size_t)b * G_ + g) * HID_ + 4 * tc;
            atomicAdd(hp + 0, acc[j].x);
            atomicAdd(hp + 1, acc[j].y);
            atomicAdd(hp + 2, acc[j].z);
            atomicAdd(hp + 3, acc[j].w);
        }
    }
}

// ---------------------------------------------------------------------------
// BatchNorm (per-g stats over (B, 256)) + ReLU, in place. Block per g.
// ---------------------------------------------------------------------------
__global__ __launch_bounds__(256) void bnrelu_k(float* __restrict__ buf,
                                                const float* __restrict__ gamma,
                                                const float* __restrict__ beta) {
    int g = blockIdx.x, t = threadIdx.x;
    float v[B_];
    float s = 0.f, ss = 0.f;
#pragma unroll
    for (int b = 0; b < B_; ++b) {
        float xv = buf[((size_t)b * G_ + g) * HID_ + t];
        v[b] = xv;
        s += xv;
        ss += xv * xv;
    }
#pragma unroll
    for (int o = 32; o > 0; o >>= 1) {
        s  += __shfl_down(s, o);
        ss += __shfl_down(ss, o);
    }
    __shared__ float rs[4], rss[4];
    int wave = t >> 6, lane = t & 63;
    if (lane == 0) { rs[wave] = s; rss[wave] = ss; }
    __syncthreads();
    float S  = rs[0] + rs[1] + rs[2] + rs[3];
    float SS = rss[0] + rss[1] + rss[2] + rss[3];
    const float inv = 1.0f / (float)(B_ * HID_);
    float mean = S * inv;
    float var  = SS * inv - mean * mean;       // biased, matches jnp.var
    float sc = gamma[g] * rsqrtf(var + EPS_);
    float sh = beta[g] - mean * sc;
#pragma unroll
    for (int b = 0; b < B_; ++b) {
        float y = v[b] * sc + sh;
        buf[((size_t)b * G_ + g) * HID_ + t] = fmaxf(y, 0.f);
    }
}

// ---------------------------------------------------------------------------
// z[row, :] = b2 + h[row, :] . W2t   — 16 rows/block, thread = 4 cols x 4 rows
// ---------------------------------------------------------------------------
#define GR_ 16
__global__ __launch_bounds__(256) void gemm2_k(const float4* __restrict__ h4,
                                               const float4* __restrict__ w2t4,
                                               const float* __restrict__ b2,
                                               float4* __restrict__ z4) {
    int row0 = blockIdx.x * GR_;
    int t = threadIdx.x;
    __shared__ float lh[GR_][HID_];    // 16 KB
#pragma unroll
    for (int p = 0; p < 4; ++p) {
        int i = p * 256 + t;           // 0..1023 over 16 rows x 64 float4
        int r = i >> 6, q = i & 63;
        float4 v = h4[(size_t)(row0 + r) * 64 + q];
        *reinterpret_cast<float4*>(&lh[r][4 * q]) = v;
    }
    __syncthreads();
    int tc = t & 63;                   // cols 4*tc..+3
    int tb = t >> 6;                   // rows 4*tb..+3 (wave-uniform)
    float4 bb = ((const float4*)b2)[tc];
    float4 acc[4] = {bb, bb, bb, bb};
    for (int k = 0; k < HID_; ++k) {
        float4 wv = w2t4[(size_t)k * 64 + tc];   // coalesced, L1/L2 resident
#pragma unroll
        for (int j = 0; j < 4; ++j) {
            float xv = lh[4 * tb + j][k];         // LDS broadcast
            acc[j].x += xv * wv.x;
            acc[j].y += xv * wv.y;
            acc[j].z += xv * wv.z;
            acc[j].w += xv * wv.w;
        }
    }
#pragma unroll
    for (int j = 0; j < 4; ++j)
        z4[(size_t)(row0 + 4 * tb + j) * 64 + tc] = acc[j];
}

// ---------------------------------------------------------------------------
extern "C" void kernel_launch(void* const* d_in, const int* in_sizes, int n_in,
                              void* d_out, int out_size, void* d_ws, size_t ws_size,
                              hipStream_t stream) {
    const float* x    = (const float*)d_in[0];
    const float* mask = (const float*)d_in[1];
    const float* W1   = (const float*)d_in[2];
    const float* b1   = (const float*)d_in[3];
    const float* g1   = (const float*)d_in[4];
    const float* be1  = (const float*)d_in[5];
    const float* W2   = (const float*)d_in[6];
    const float* b2   = (const float*)d_in[7];
    const float* g2   = (const float*)d_in[8];
    const float* be2  = (const float*)d_in[9];
    float* out = (float*)d_out;

    char* ws = (char*)d_ws;
    size_t off = 0;
    auto take = [&](size_t bytes) {
        char* p = ws + off;
        off = (off + bytes + 255) & ~(size_t)255;
        return p;
    };
    float* w1t          = (float*)take((size_t)N_ * HID_ * 4);   // (N, HID)
    float* xt           = (float*)take((size_t)N_ * B_ * 4);     // (N, B)
    float* w2t          = (float*)take((size_t)HID_ * Z_ * 4);   // (HID, Z)
    float* h            = (float*)take((size_t)B_ * G_ * HID_ * 4);
    int* cnt            = (int*)take((size_t)G_ * 4);
    unsigned short* idx = (unsigned short*)take((size_t)G_ * N_ * 2);
    int* work           = (int*)take((size_t)4096 * 4);
    int* nwork          = (int*)take(256);

    hipMemsetAsync(nwork, 0, 4, stream);

    prep_k<<<PREP_GRID, 256, 0, stream>>>(W1, x, W2, mask, b1,
                                          w1t, xt, w2t, (float4*)h,
                                          cnt, idx, work, nwork);
    spacc_k<<<768, 256, 0, stream>>>((const float4*)w1t, (const float4*)xt,
                                     cnt, idx, work, nwork, h);
    bnrelu_k<<<G_, 256, 0, stream>>>(h, g1, be1);
    gemm2_k<<<(B_ * G_) / GR_, 256, 0, stream>>>((const float4*)h, (const float4*)w2t,
                                                 b2, (float4*)out);
    bnrelu_k<<<G_, 256, 0, stream>>>(out, g2, be2);
}

// Round 3
// 111.003 us; speedup vs baseline: 1.3995x; 1.3415x over previous
//
#include <hip/hip_runtime.h>

#define B_    32
#define N_    10000
#define G_    256
#define HID_  256
#define Z_    256
#define EPS_  1e-5f

// prep_k grid segmentation
#define TB_W1  2504            // 313 col-tiles x 8 row-tiles (W1: 256 x 10000)
#define TB_X   313             // x: 32 x 10000
#define TB_W2  64              // W2: 256 x 256
#define NB_CMP 256             // mask compaction, one block per g
#define PREP_GRID (TB_W1 + TB_X + TB_W2 + NB_CMP)   // 3137

#define DKB_  40               // dense-group split-K blocks
#define DCH_  250              // genes per dense chunk (40*250 = 10000)

// ---------------------------------------------------------------------------
// Tiled transpose helper: src R x C row-major -> dst C x R row-major.
// ---------------------------------------------------------------------------
__device__ inline void transpose_tile(const float* __restrict__ src,
                                      float* __restrict__ dst,
                                      int R, int C, int bx, int by, int t,
                                      float (*tile)[33]) {
    int tx = t & 31, ty = t >> 5;      // 32 x 8
    int c0 = bx * 32, r0 = by * 32;
#pragma unroll
    for (int j = 0; j < 4; ++j) {
        int r = r0 + ty + j * 8, c = c0 + tx;
        if (r < R && c < C) tile[ty + j * 8][tx] = src[(size_t)r * C + c];
    }
    __syncthreads();
#pragma unroll
    for (int j = 0; j < 4; ++j) {
        int c = c0 + ty + j * 8, r = r0 + tx;
        if (r < R && c < C) dst[(size_t)c * R + r] = tile[tx][ty + j * 8];
    }
}

// ---------------------------------------------------------------------------
// Fused prep: W1/x/W2 transposes + mask compaction (per-group gene lists).
// ---------------------------------------------------------------------------
__global__ __launch_bounds__(256) void prep_k(const float* __restrict__ W1,
                                              const float* __restrict__ x,
                                              const float* __restrict__ W2,
                                              const float* __restrict__ mask,
                                              float* __restrict__ w1t,
                                              float* __restrict__ xt,
                                              float* __restrict__ w2t,
                                              int* __restrict__ cnt,
                                              unsigned short* __restrict__ idx) {
    __shared__ float tile[32][33];
    __shared__ int c;
    int bid = blockIdx.x, t = threadIdx.x;

    if (bid < TB_W1) {
        transpose_tile(W1, w1t, HID_, N_, bid % 313, bid / 313, t, tile);
    } else if (bid < TB_W1 + TB_X) {
        transpose_tile(x, xt, B_, N_, bid - TB_W1, 0, t, tile);
    } else if (bid < TB_W1 + TB_X + TB_W2) {
        int b = bid - (TB_W1 + TB_X);
        transpose_tile(W2, w2t, Z_, HID_, b % 8, b / 8, t, tile);
    } else {
        int g = bid - (TB_W1 + TB_X + TB_W2);
        if (t == 0) c = 0;
        __syncthreads();
        for (int n = t; n < N_; n += 256) {
            if (mask[(size_t)g * N_ + n] != 0.0f) {
                int p = atomicAdd(&c, 1);          // LDS atomic only
                idx[(size_t)g * N_ + p] = (unsigned short)n;
            }
        }
        __syncthreads();
        if (t == 0) cnt[g] = c;
    }
}

// ---------------------------------------------------------------------------
// Sparse group-GEMM, zero atomics.  bid < 255: block owns group g entirely,
// writes h[g][b][t] (+b1).  bid >= 255: dense group split-K chunk -> hpart.
// 1024 threads = 16 waves; waves are COLUMN-split (no duplicated W loads):
//   w = t>>6, l = t&63
//   tc = (w&3)*16 + (l&15)   -> float4 column of HID (0..63)
//   tb = (l>>4) + 4*(w>>2)   -> batch pair (batches 2tb, 2tb+1)
// ---------------------------------------------------------------------------
__global__ __launch_bounds__(1024) void spgemm_k(const float4* __restrict__ w1t4,
                                                 const float4* __restrict__ xt4,
                                                 const int* __restrict__ cnt,
                                                 const unsigned short* __restrict__ idx,
                                                 const float4* __restrict__ b1_4,
                                                 float* __restrict__ h,
                                                 float* __restrict__ hpart) {
    __shared__ int ns[256];
    __shared__ float4 xs[256][9];      // [gene][b/4] + pad
    const int bid = blockIdx.x, t = threadIdx.x;
    const int w = t >> 6, l = t & 63;
    const int tc = (w & 3) * 16 + (l & 15);
    const int tb = (l >> 4) + 4 * (w >> 2);

    int g, k0, kend;
    float* dst;
    bool addb;
    if (bid < 255) {
        g = bid; k0 = 0; kend = cnt[g];
        dst = h + (size_t)g * (B_ * HID_); addb = true;
    } else {
        int kb = bid - 255;
        g = 255; k0 = kb * DCH_; kend = k0 + DCH_;
        dst = hpart + (size_t)kb * (B_ * HID_); addb = false;
    }

    float4 a0 = {0.f, 0.f, 0.f, 0.f}, a1 = {0.f, 0.f, 0.f, 0.f};
    const float* xsf = (const float*)xs;

    for (int base = k0; base < kend; base += 256) {
        int kn = min(256, kend - base);
        __syncthreads();                           // protect xs/ns reuse
        if (t < kn) ns[t] = idx[(size_t)g * N_ + base + t];
        __syncthreads();
        for (int i = t; i < kn * 8; i += 1024)
            xs[i >> 3][i & 7] = xt4[(size_t)ns[i >> 3] * 8 + (i & 7)];
        __syncthreads();

#pragma unroll 4
        for (int k = 0; k < kn; ++k) {
            float4 wv = w1t4[(size_t)ns[k] * 64 + tc];   // 256B/wave, coalesced
            float2 xv = *(const float2*)(xsf + k * 36 + 2 * tb); // LDS b64
            a0.x = fmaf(xv.x, wv.x, a0.x);
            a0.y = fmaf(xv.x, wv.y, a0.y);
            a0.z = fmaf(xv.x, wv.z, a0.z);
            a0.w = fmaf(xv.x, wv.w, a0.w);
            a1.x = fmaf(xv.y, wv.x, a1.x);
            a1.y = fmaf(xv.y, wv.y, a1.y);
            a1.z = fmaf(xv.y, wv.z, a1.z);
            a1.w = fmaf(xv.y, wv.w, a1.w);
        }
    }

    if (addb) {
        float4 bb = b1_4[tc];
        a0.x += bb.x; a0.y += bb.y; a0.z += bb.z; a0.w += bb.w;
        a1.x += bb.x; a1.y += bb.y; a1.z += bb.z; a1.w += bb.w;
    }
    float4* df = (float4*)dst;
    df[(size_t)(2 * tb) * 64 + tc]     = a0;   // plain stores, single writer
    df[(size_t)(2 * tb + 1) * 64 + tc] = a1;
}

// ---------------------------------------------------------------------------
// Dense-group split-K reduction: h[255][i] = b1 + sum_kb hpart[kb][i]
// ---------------------------------------------------------------------------
__global__ __launch_bounds__(256) void reduce_k(const float* __restrict__ hpart,
                                                const float* __restrict__ b1,
                                                float* __restrict__ h) {
    int i = blockIdx.x * 256 + threadIdx.x;   // 0..8191
    float s = b1[i & (HID_ - 1)];
#pragma unroll
    for (int kb = 0; kb < DKB_; ++kb) s += hpart[(size_t)kb * (B_ * HID_) + i];
    h[(size_t)255 * (B_ * HID_) + i] = s;
}

// ---------------------------------------------------------------------------
// Fused BN1+ReLU -> GEMM2 -> BN2+ReLU.  One block per group g (512 threads).
// h[g] (32x256) fits in LDS = exact BN1 stats scope; the block's GEMM
// accumulators are exactly z[g] = exact BN2 stats scope. No extra traffic.
// ---------------------------------------------------------------------------
__global__ __launch_bounds__(512) void fused_k(const float4* __restrict__ h4,
                                               const float4* __restrict__ w2t4,
                                               const float* __restrict__ g1,
                                               const float* __restrict__ be1,
                                               const float4* __restrict__ b2_4,
                                               const float* __restrict__ g2,
                                               const float* __restrict__ be2,
                                               float4* __restrict__ z4) {
    __shared__ float lh[32][260];      // 32 rows(b) x 256(c), pad 260
    __shared__ float rs[8], rss[8];
    const int g = blockIdx.x, t = threadIdx.x;
    const int w = t >> 6, l = t & 63;
    const int tc = (w & 3) * 16 + (l & 15);    // float4 z-col (0..63)
    const int rg = (l >> 4) + 4 * (w >> 2);    // row group: rows 4rg..4rg+3

    // ---- load h[g] (2048 float4, coalesced), accumulate BN1 stats ----
    float s = 0.f, ss = 0.f;
    float4 mine[4];
#pragma unroll
    for (int p = 0; p < 4; ++p) {
        int i = p * 512 + t;                   // 0..2047
        float4 v = h4[(size_t)g * 2048 + i];
        mine[p] = v;
        int r = i >> 6, q = i & 63;
        *(float4*)&lh[r][4 * q] = v;
        s  += v.x + v.y + v.z + v.w;
        ss += v.x * v.x + v.y * v.y + v.z * v.z + v.w * v.w;
    }
#pragma unroll
    for (int o = 32; o > 0; o >>= 1) { s += __shfl_down(s, o); ss += __shfl_down(ss, o); }
    if (l == 0) { rs[w] = s; rss[w] = ss; }
    __syncthreads();
    float S = 0.f, SS = 0.f;
#pragma unroll
    for (int j = 0; j < 8; ++j) { S += rs[j]; SS += rss[j]; }
    const float inv = 1.0f / (float)(B_ * HID_);
    float mean = S * inv;
    float var  = SS * inv - mean * mean;
    float sc = g1[g] * rsqrtf(var + EPS_);
    float sh = be1[g] - mean * sc;

    // ---- normalize + ReLU own elements in LDS ----
#pragma unroll
    for (int p = 0; p < 4; ++p) {
        int i = p * 512 + t;
        int r = i >> 6, q = i & 63;
        float4 v = mine[p];
        v.x = fmaxf(fmaf(v.x, sc, sh), 0.f);
        v.y = fmaxf(fmaf(v.y, sc, sh), 0.f);
        v.z = fmaxf(fmaf(v.z, sc, sh), 0.f);
        v.w = fmaxf(fmaf(v.w, sc, sh), 0.f);
        *(float4*)&lh[r][4 * q] = v;
    }
    __syncthreads();

    // ---- GEMM2: acc[j] (rows 4rg+j, z-cols 4tc..4tc+3) ----
    float4 bb = b2_4[tc];
    float4 acc[4] = {bb, bb, bb, bb};
    for (int k = 0; k < HID_; ++k) {
        float4 wv = w2t4[(size_t)k * 64 + tc];         // 256B/wave
#pragma unroll
        for (int j = 0; j < 4; ++j) {
            float xv = lh[4 * rg + j][k];              // LDS broadcast
            acc[j].x = fmaf(xv, wv.x, acc[j].x);
            acc[j].y = fmaf(xv, wv.y, acc[j].y);
            acc[j].z = fmaf(xv, wv.z, acc[j].z);
            acc[j].w = fmaf(xv, wv.w, acc[j].w);
        }
    }

    // ---- BN2 stats over the block's 8192 acc values ----
    s = 0.f; ss = 0.f;
#pragma unroll
    for (int j = 0; j < 4; ++j) {
        s  += acc[j].x + acc[j].y + acc[j].z + acc[j].w;
        ss += acc[j].x * acc[j].x + acc[j].y * acc[j].y
            + acc[j].z * acc[j].z + acc[j].w * acc[j].w;
    }
#pragma unroll
    for (int o = 32; o > 0; o >>= 1) { s += __shfl_down(s, o); ss += __shfl_down(ss, o); }
    if (l == 0) { rs[w] = s; rss[w] = ss; }   // safe: all BN1 reads done pre-GEMM sync
    __syncthreads();
    S = 0.f; SS = 0.f;
#pragma unroll
    for (int j = 0; j < 8; ++j) { S += rs[j]; SS += rss[j]; }
    mean = S * inv;
    var  = SS * inv - mean * mean;
    float sc2 = g2[g] * rsqrtf(var + EPS_);
    float sh2 = be2[g] - mean * sc2;

    // ---- BN2 + ReLU + store to out[b, g, z] ----
#pragma unroll
    for (int j = 0; j < 4; ++j) {
        int b = 4 * rg + j;
        float4 v;
        v.x = fmaxf(fmaf(acc[j].x, sc2, sh2), 0.f);
        v.y = fmaxf(fmaf(acc[j].y, sc2, sh2), 0.f);
        v.z = fmaxf(fmaf(acc[j].z, sc2, sh2), 0.f);
        v.w = fmaxf(fmaf(acc[j].w, sc2, sh2), 0.f);
        z4[(size_t)(b * G_ + g) * 64 + tc] = v;
    }
}

// ---------------------------------------------------------------------------
extern "C" void kernel_launch(void* const* d_in, const int* in_sizes, int n_in,
                              void* d_out, int out_size, void* d_ws, size_t ws_size,
                              hipStream_t stream) {
    const float* x    = (const float*)d_in[0];
    const float* mask = (const float*)d_in[1];
    const float* W1   = (const float*)d_in[2];
    const float* b1   = (const float*)d_in[3];
    const float* g1   = (const float*)d_in[4];
    const float* be1  = (const float*)d_in[5];
    const float* W2   = (const float*)d_in[6];
    const float* b2   = (const float*)d_in[7];
    const float* g2   = (const float*)d_in[8];
    const float* be2  = (const float*)d_in[9];
    float* out = (float*)d_out;

    char* ws = (char*)d_ws;
    size_t off = 0;
    auto take = [&](size_t bytes) {
        char* p = ws + off;
        off = (off + bytes + 255) & ~(size_t)255;
        return p;
    };
    float* w1t          = (float*)take((size_t)N_ * HID_ * 4);       // (N, HID)
    float* xt           = (float*)take((size_t)N_ * B_ * 4);         // (N, B)
    float* w2t          = (float*)take((size_t)HID_ * Z_ * 4);       // (HID, Z)
    float* h            = (float*)take((size_t)G_ * B_ * HID_ * 4);  // [g][b][c]
    float* hpart        = (float*)take((size_t)DKB_ * B_ * HID_ * 4);
    int* cnt            = (int*)take((size_t)G_ * 4);
    unsigned short* idx = (unsigned short*)take((size_t)G_ * N_ * 2);

    prep_k<<<PREP_GRID, 256, 0, stream>>>(W1, x, W2, mask, w1t, xt, w2t, cnt, idx);
    spgemm_k<<<255 + DKB_, 1024, 0, stream>>>((const float4*)w1t, (const float4*)xt,
                                              cnt, idx, (const float4*)b1, h, hpart);
    reduce_k<<<(B_ * HID_) / 256, 256, 0, stream>>>(hpart, b1, h);
    fused_k<<<G_, 512, 0, stream>>>((const float4*)h, (const float4*)w2t,
                                    g1, be1, (const float4*)b2, g2, be2,
                                    (float4*)out);
}

// Round 4
// 89.139 us; speedup vs baseline: 1.7428x; 1.2453x over previous
//
#include <hip/hip_runtime.h>

#define B_    32
#define N_    10000
#define G_    256
#define HID_  256
#define Z_    256
#define EPS_  1e-5f

// prep_k grid segmentation
#define TB_W1  2504            // 313 col-tiles x 8 row-tiles (W1: 256 x 10000)
#define TB_X   313             // x: 32 x 10000
#define TB_W2  64              // W2: 256 x 256
#define NB_CMP 256             // mask compaction, one block per g
#define PREP_GRID (TB_W1 + TB_X + TB_W2 + NB_CMP)   // 3137

#define DKB_  40               // dense-group split-K blocks
#define DCH_  250              // genes per dense chunk (40*250 = 10000)

// ---------------------------------------------------------------------------
// Tiled transpose helper: src R x C row-major -> dst C x R row-major.
// ---------------------------------------------------------------------------
__device__ inline void transpose_tile(const float* __restrict__ src,
                                      float* __restrict__ dst,
                                      int R, int C, int bx, int by, int t,
                                      float (*tile)[33]) {
    int tx = t & 31, ty = t >> 5;      // 32 x 8
    int c0 = bx * 32, r0 = by * 32;
#pragma unroll
    for (int j = 0; j < 4; ++j) {
        int r = r0 + ty + j * 8, c = c0 + tx;
        if (r < R && c < C) tile[ty + j * 8][tx] = src[(size_t)r * C + c];
    }
    __syncthreads();
#pragma unroll
    for (int j = 0; j < 4; ++j) {
        int c = c0 + ty + j * 8, r = r0 + tx;
        if (r < R && c < C) dst[(size_t)c * R + r] = tile[tx][ty + j * 8];
    }
}

// ---------------------------------------------------------------------------
// Fused prep: W1/x/W2 transposes + mask compaction (per-group gene lists).
// ---------------------------------------------------------------------------
__global__ __launch_bounds__(256) void prep_k(const float* __restrict__ W1,
                                              const float* __restrict__ x,
                                              const float* __restrict__ W2,
                                              const float* __restrict__ mask,
                                              float* __restrict__ w1t,
                                              float* __restrict__ xt,
                                              float* __restrict__ w2t,
                                              int* __restrict__ cnt,
                                              unsigned short* __restrict__ idx) {
    __shared__ float tile[32][33];
    __shared__ int c;
    int bid = blockIdx.x, t = threadIdx.x;

    if (bid < TB_W1) {
        transpose_tile(W1, w1t, HID_, N_, bid % 313, bid / 313, t, tile);
    } else if (bid < TB_W1 + TB_X) {
        transpose_tile(x, xt, B_, N_, bid - TB_W1, 0, t, tile);
    } else if (bid < TB_W1 + TB_X + TB_W2) {
        int b = bid - (TB_W1 + TB_X);
        transpose_tile(W2, w2t, Z_, HID_, b % 8, b / 8, t, tile);
    } else {
        int g = bid - (TB_W1 + TB_X + TB_W2);
        if (t == 0) c = 0;
        __syncthreads();
        for (int n = t; n < N_; n += 256) {
            if (mask[(size_t)g * N_ + n] != 0.0f) {
                int p = atomicAdd(&c, 1);          // LDS atomic only
                idx[(size_t)g * N_ + p] = (unsigned short)n;
            }
        }
        __syncthreads();
        if (t == 0) cnt[g] = c;
    }
}

// ---------------------------------------------------------------------------
// Sparse group-GEMM, zero atomics.  bid < 255: block owns group g entirely,
// writes h[g][b][t] (+b1).  bid >= 255: dense group split-K chunk -> hpart.
// 512 threads = 8 waves:
//   tc = t & 63   -> float4 HID column; a wave's 64 lanes span the full
//                    1KB W-row (perfectly coalesced, max bytes in flight)
//   tb = t >> 6   -> batches 4tb..4tb+3 (wave-uniform -> xs LDS broadcast)
// Per gene per thread: 1 indep float4 load + 1 LDS broadcast + 16 fmaf.
// ---------------------------------------------------------------------------
__global__ __launch_bounds__(512) void spgemm_k(const float4* __restrict__ w1t4,
                                                const float4* __restrict__ xt4,
                                                const int* __restrict__ cnt,
                                                const unsigned short* __restrict__ idx,
                                                const float4* __restrict__ b1_4,
                                                float* __restrict__ h,
                                                float* __restrict__ hpart) {
    __shared__ int ns[256];
    __shared__ float4 xs[256][9];      // [gene][b/4] + pad
    const int bid = blockIdx.x, t = threadIdx.x;
    const int tc = t & 63;
    const int tb = t >> 6;

    int g, k0, kend;
    float* dst;
    bool addb;
    if (bid < 255) {
        g = bid; k0 = 0; kend = cnt[g];
        dst = h + (size_t)g * (B_ * HID_); addb = true;
    } else {
        int kb = bid - 255;
        g = 255; k0 = kb * DCH_; kend = k0 + DCH_;
        dst = hpart + (size_t)kb * (B_ * HID_); addb = false;
    }

    float4 a0 = {0.f, 0.f, 0.f, 0.f}, a1 = a0, a2 = a0, a3 = a0;

    for (int base = k0; base < kend; base += 256) {
        int kn = min(256, kend - base);
        __syncthreads();                           // protect ns/xs reuse
        if (t < kn) ns[t] = idx[(size_t)g * N_ + base + t];
        __syncthreads();
        for (int i = t; i < kn * 8; i += 512)
            xs[i >> 3][i & 7] = xt4[(size_t)ns[i >> 3] * 8 + (i & 7)];
        __syncthreads();

#pragma unroll 8
        for (int k = 0; k < kn; ++k) {
            float4 wv = w1t4[(size_t)ns[k] * 64 + tc];   // 1KB/wave, coalesced
            float4 xv = xs[k][tb];                        // LDS broadcast
            a0.x = fmaf(xv.x, wv.x, a0.x);
            a0.y = fmaf(xv.x, wv.y, a0.y);
            a0.z = fmaf(xv.x, wv.z, a0.z);
            a0.w = fmaf(xv.x, wv.w, a0.w);
            a1.x = fmaf(xv.y, wv.x, a1.x);
            a1.y = fmaf(xv.y, wv.y, a1.y);
            a1.z = fmaf(xv.y, wv.z, a1.z);
            a1.w = fmaf(xv.y, wv.w, a1.w);
            a2.x = fmaf(xv.z, wv.x, a2.x);
            a2.y = fmaf(xv.z, wv.y, a2.y);
            a2.z = fmaf(xv.z, wv.z, a2.z);
            a2.w = fmaf(xv.z, wv.w, a2.w);
            a3.x = fmaf(xv.w, wv.x, a3.x);
            a3.y = fmaf(xv.w, wv.y, a3.y);
            a3.z = fmaf(xv.w, wv.z, a3.z);
            a3.w = fmaf(xv.w, wv.w, a3.w);
        }
    }

    if (addb) {
        float4 bb = b1_4[tc];
        a0.x += bb.x; a0.y += bb.y; a0.z += bb.z; a0.w += bb.w;
        a1.x += bb.x; a1.y += bb.y; a1.z += bb.z; a1.w += bb.w;
        a2.x += bb.x; a2.y += bb.y; a2.z += bb.z; a2.w += bb.w;
        a3.x += bb.x; a3.y += bb.y; a3.z += bb.z; a3.w += bb.w;
    }
    float4* df = (float4*)dst;
    df[(size_t)(4 * tb + 0) * 64 + tc] = a0;   // plain stores, single writer
    df[(size_t)(4 * tb + 1) * 64 + tc] = a1;
    df[(size_t)(4 * tb + 2) * 64 + tc] = a2;
    df[(size_t)(4 * tb + 3) * 64 + tc] = a3;
}

// ---------------------------------------------------------------------------
// Dense-group split-K reduction: h[255][i] = b1 + sum_kb hpart[kb][i]
// ---------------------------------------------------------------------------
__global__ __launch_bounds__(256) void reduce_k(const float* __restrict__ hpart,
                                                const float* __restrict__ b1,
                                                float* __restrict__ h) {
    int i = blockIdx.x * 256 + threadIdx.x;   // 0..8191
    float s = b1[i & (HID_ - 1)];
#pragma unroll
    for (int kb = 0; kb < DKB_; ++kb) s += hpart[(size_t)kb * (B_ * HID_) + i];
    h[(size_t)255 * (B_ * HID_) + i] = s;
}

// ---------------------------------------------------------------------------
// Fused BN1+ReLU -> GEMM2 -> BN2+ReLU.  One block per group g (512 threads).
// ---------------------------------------------------------------------------
__global__ __launch_bounds__(512) void fused_k(const float4* __restrict__ h4,
                                               const float4* __restrict__ w2t4,
                                               const float* __restrict__ g1,
                                               const float* __restrict__ be1,
                                               const float4* __restrict__ b2_4,
                                               const float* __restrict__ g2,
                                               const float* __restrict__ be2,
                                               float4* __restrict__ z4) {
    __shared__ float lh[32][260];      // 32 rows(b) x 256(c), pad 260
    __shared__ float rs[8], rss[8];
    const int g = blockIdx.x, t = threadIdx.x;
    const int w = t >> 6, l = t & 63;
    const int tc = (w & 3) * 16 + (l & 15);    // float4 z-col (0..63)
    const int rg = (l >> 4) + 4 * (w >> 2);    // row group: rows 4rg..4rg+3

    // ---- load h[g] (2048 float4, coalesced), accumulate BN1 stats ----
    float s = 0.f, ss = 0.f;
    float4 mine[4];
#pragma unroll
    for (int p = 0; p < 4; ++p) {
        int i = p * 512 + t;                   // 0..2047
        float4 v = h4[(size_t)g * 2048 + i];
        mine[p] = v;
        int r = i >> 6, q = i & 63;
        *(float4*)&lh[r][4 * q] = v;
        s  += v.x + v.y + v.z + v.w;
        ss += v.x * v.x + v.y * v.y + v.z * v.z + v.w * v.w;
    }
#pragma unroll
    for (int o = 32; o > 0; o >>= 1) { s += __shfl_down(s, o); ss += __shfl_down(ss, o); }
    if (l == 0) { rs[w] = s; rss[w] = ss; }
    __syncthreads();
    float S = 0.f, SS = 0.f;
#pragma unroll
    for (int j = 0; j < 8; ++j) { S += rs[j]; SS += rss[j]; }
    const float inv = 1.0f / (float)(B_ * HID_);
    float mean = S * inv;
    float var  = SS * inv - mean * mean;
    float sc = g1[g] * rsqrtf(var + EPS_);
    float sh = be1[g] - mean * sc;

    // ---- normalize + ReLU own elements in LDS ----
#pragma unroll
    for (int p = 0; p < 4; ++p) {
        int i = p * 512 + t;
        int r = i >> 6, q = i & 63;
        float4 v = mine[p];
        v.x = fmaxf(fmaf(v.x, sc, sh), 0.f);
        v.y = fmaxf(fmaf(v.y, sc, sh), 0.f);
        v.z = fmaxf(fmaf(v.z, sc, sh), 0.f);
        v.w = fmaxf(fmaf(v.w, sc, sh), 0.f);
        *(float4*)&lh[r][4 * q] = v;
    }
    __syncthreads();

    // ---- GEMM2: acc[j] (rows 4rg+j, z-cols 4tc..4tc+3) ----
    float4 bb = b2_4[tc];
    float4 acc[4] = {bb, bb, bb, bb};
    for (int k = 0; k < HID_; ++k) {
        float4 wv = w2t4[(size_t)k * 64 + tc];         // 256B/wave
#pragma unroll
        for (int j = 0; j < 4; ++j) {
            float xv = lh[4 * rg + j][k];              // LDS broadcast
            acc[j].x = fmaf(xv, wv.x, acc[j].x);
            acc[j].y = fmaf(xv, wv.y, acc[j].y);
            acc[j].z = fmaf(xv, wv.z, acc[j].z);
            acc[j].w = fmaf(xv, wv.w, acc[j].w);
        }
    }

    // ---- BN2 stats over the block's 8192 acc values ----
    s = 0.f; ss = 0.f;
#pragma unroll
    for (int j = 0; j < 4; ++j) {
        s  += acc[j].x + acc[j].y + acc[j].z + acc[j].w;
        ss += acc[j].x * acc[j].x + acc[j].y * acc[j].y
            + acc[j].z * acc[j].z + acc[j].w * acc[j].w;
    }
#pragma unroll
    for (int o = 32; o > 0; o >>= 1) { s += __shfl_down(s, o); ss += __shfl_down(ss, o); }
    if (l == 0) { rs[w] = s; rss[w] = ss; }   // safe: all BN1 reads done pre-GEMM sync
    __syncthreads();
    S = 0.f; SS = 0.f;
#pragma unroll
    for (int j = 0; j < 8; ++j) { S += rs[j]; SS += rss[j]; }
    mean = S * inv;
    var  = SS * inv - mean * mean;
    float sc2 = g2[g] * rsqrtf(var + EPS_);
    float sh2 = be2[g] - mean * sc2;

    // ---- BN2 + ReLU + store to out[b, g, z] ----
#pragma unroll
    for (int j = 0; j < 4; ++j) {
        int b = 4 * rg + j;
        float4 v;
        v.x = fmaxf(fmaf(acc[j].x, sc2, sh2), 0.f);
        v.y = fmaxf(fmaf(acc[j].y, sc2, sh2), 0.f);
        v.z = fmaxf(fmaf(acc[j].z, sc2, sh2), 0.f);
        v.w = fmaxf(fmaf(acc[j].w, sc2, sh2), 0.f);
        z4[(size_t)(b * G_ + g) * 64 + tc] = v;
    }
}

// ---------------------------------------------------------------------------
extern "C" void kernel_launch(void* const* d_in, const int* in_sizes, int n_in,
                              void* d_out, int out_size, void* d_ws, size_t ws_size,
                              hipStream_t stream) {
    const float* x    = (const float*)d_in[0];
    const float* mask = (const float*)d_in[1];
    const float* W1   = (const float*)d_in[2];
    const float* b1   = (const float*)d_in[3];
    const float* g1   = (const float*)d_in[4];
    const float* be1  = (const float*)d_in[5];
    const float* W2   = (const float*)d_in[6];
    const float* b2   = (const float*)d_in[7];
    const float* g2   = (const float*)d_in[8];
    const float* be2  = (const float*)d_in[9];
    float* out = (float*)d_out;

    char* ws = (char*)d_ws;
    size_t off = 0;
    auto take = [&](size_t bytes) {
        char* p = ws + off;
        off = (off + bytes + 255) & ~(size_t)255;
        return p;
    };
    float* w1t          = (float*)take((size_t)N_ * HID_ * 4);       // (N, HID)
    float* xt           = (float*)take((size_t)N_ * B_ * 4);         // (N, B)
    float* w2t          = (float*)take((size_t)HID_ * Z_ * 4);       // (HID, Z)
    float* h            = (float*)take((size_t)G_ * B_ * HID_ * 4);  // [g][b][c]
    float* hpart        = (float*)take((size_t)DKB_ * B_ * HID_ * 4);
    int* cnt            = (int*)take((size_t)G_ * 4);
    unsigned short* idx = (unsigned short*)take((size_t)G_ * N_ * 2);

    prep_k<<<PREP_GRID, 256, 0, stream>>>(W1, x, W2, mask, w1t, xt, w2t, cnt, idx);
    spgemm_k<<<255 + DKB_, 512, 0, stream>>>((const float4*)w1t, (const float4*)xt,
                                             cnt, idx, (const float4*)b1, h, hpart);
    reduce_k<<<(B_ * HID_) / 256, 256, 0, stream>>>(hpart, b1, h);
    fused_k<<<G_, 512, 0, stream>>>((const float4*)h, (const float4*)w2t,
                                    g1, be1, (const float4*)b2, g2, be2,
                                    (float4*)out);
}